// Round 4
// baseline (348.775 us; speedup 1.0000x reference)
//
#include <hip/hip_runtime.h>
#include <hip/hip_bf16.h>

typedef __bf16 bf16_t;
typedef __bf16 bf16x8 __attribute__((ext_vector_type(8)));
typedef float f32x4 __attribute__((ext_vector_type(4)));

// Problem constants
#define NB 2
#define NH 24
#define LQ 4608
#define DD 128
#define LIP 16
#define CDIM 4096
#define HIDDEN 3072

// Kernel A tiling
#define CS 8                 // C splits (split-K width)
#define CB (CDIM / CS)       // 512 C per block
#define CCHUNK 128           // LDS-staged C chunk
#define NCHUNK (CB / CCHUNK) // 4
#define HB 128               // hidden per block
#define HBLKS (HIDDEN / HB)  // 24

// ws layout (bytes)
#define P_FLOATS_PER_KV ((size_t)CS * 32 * HIDDEN)          // 786,432
#define P_BYTES ((size_t)2 * P_FLOATS_PER_KV * 4)           // 6,291,456
#define K16_OFF P_BYTES
#define K16_BYTES ((size_t)NB * NH * LIP * DD * 2)          // 196,608
#define VT_OFF (K16_OFF + K16_BYTES)

// ---------------------------------------------------------------------------
// Kernel A: partial projection GEMM.
// grid (24, 8, 2), block 256. Each block: 128 hidden x 32 rows over a 512-wide
// C slice, staged in 4 LDS chunks of [32][128]. Memory-bound on the 96 MB W
// read (disjoint across blocks).
// thread = (hg = t>>4 -> 8 hidden rows, rg = t&15 -> rows rg, rg+16)
// ---------------------------------------------------------------------------
__global__ __launch_bounds__(256) void kA(const float* __restrict__ img,
                                          const float* __restrict__ Wk,
                                          const float* __restrict__ Wv,
                                          float* __restrict__ P) {
  const int hblk = blockIdx.x, cs = blockIdx.y, kv = blockIdx.z;
  const float* __restrict__ W = kv ? Wv : Wk;
  float* __restrict__ Pout = P + (size_t)kv * P_FLOATS_PER_KV;

  __shared__ float s_img[32 * 132];  // 32 rows x 128 cols, stride 132 (pad)
  const int t = threadIdx.x;
  const int c0 = cs * CB;

  const int hg = t >> 4;   // 0..15 -> 8 hidden rows each
  const int rg = t & 15;   // 0..15 -> rows rg, rg+16
  const int hbase = hblk * HB + hg * 8;

  float acc[8][2];
#pragma unroll
  for (int j = 0; j < 8; ++j)
#pragma unroll
    for (int i = 0; i < 2; ++i) acc[j][i] = 0.0f;

  for (int cc = 0; cc < NCHUNK; ++cc) {
    if (cc) __syncthreads();  // protect LDS reuse
    // Stage image chunk [32][128] (coalesced)
#pragma unroll
    for (int i = 0; i < 4; ++i) {
      int s = i * 256 + t;
      int row = s >> 5;
      int col4 = (s & 31) * 4;
      float4 v = *(const float4*)(img + (size_t)row * CDIM + c0 + cc * CCHUNK + col4);
      *(float4*)(s_img + row * 132 + col4) = v;
    }
    __syncthreads();

    const float* __restrict__ Wbase = W + (size_t)hbase * CDIM + c0 + cc * CCHUNK;

#pragma unroll 2
    for (int c4 = 0; c4 < CCHUNK / 4; ++c4) {
      float4 w[8];
#pragma unroll
      for (int j = 0; j < 8; ++j)
        w[j] = *(const float4*)(Wbase + (size_t)j * CDIM + c4 * 4);
      float4 im[2];
#pragma unroll
      for (int i = 0; i < 2; ++i)
        im[i] = *(const float4*)(s_img + (rg + 16 * i) * 132 + c4 * 4);
#pragma unroll
      for (int j = 0; j < 8; ++j) {
#pragma unroll
        for (int i = 0; i < 2; ++i) {
          float a = acc[j][i];
          a = fmaf(w[j].x, im[i].x, a);
          a = fmaf(w[j].y, im[i].y, a);
          a = fmaf(w[j].z, im[i].z, a);
          a = fmaf(w[j].w, im[i].w, a);
          acc[j][i] = a;
        }
      }
    }
  }

#pragma unroll
  for (int i = 0; i < 2; ++i) {
    int r = rg + 16 * i;
    float* dst = Pout + (size_t)(cs * 32 + r) * HIDDEN + hblk * HB + hg * 8;
    float4 lo = {acc[0][i], acc[1][i], acc[2][i], acc[3][i]};
    float4 hi = {acc[4][i], acc[5][i], acc[6][i], acc[7][i]};
    *(float4*)(dst) = lo;
    *(float4*)(dst + 4) = hi;
  }
}

// ---------------------------------------------------------------------------
// Kernel A2: reduce partials, RMSNorm, fold attn scale into K, emit
//   K16 bf16 [b][h][key][d]   (MFMA A-frag friendly)
//   VT  bf16 [b][h][d][key]   (MFMA B-frag friendly, transposed)
// grid 48 (= b*24+h), block 256: thread = (key = t>>4, dpos = t&15 -> 8 d's)
// ---------------------------------------------------------------------------
__global__ __launch_bounds__(256) void kA2(const float* __restrict__ P,
                                           bf16_t* __restrict__ K16,
                                           bf16_t* __restrict__ VT) {
  const int bh = blockIdx.x;
  const int b = bh / NH, h = bh % NH;
  const int t = threadIdx.x;
  const int key = t >> 4, dpos = t & 15;

  const size_t rowsel = (size_t)(b * 16 + key) * HIDDEN + h * DD + dpos * 8;

  float xk[8], xv[8];
#pragma unroll
  for (int j = 0; j < 8; ++j) { xk[j] = 0.0f; xv[j] = 0.0f; }

  const float* __restrict__ Pk = P + rowsel;
  const float* __restrict__ Pv = P + P_FLOATS_PER_KV + rowsel;
#pragma unroll
  for (int cs = 0; cs < CS; ++cs) {
    const float* p = Pk + (size_t)cs * (32 * HIDDEN);
    float4 a = *(const float4*)(p);
    float4 c = *(const float4*)(p + 4);
    xk[0] += a.x; xk[1] += a.y; xk[2] += a.z; xk[3] += a.w;
    xk[4] += c.x; xk[5] += c.y; xk[6] += c.z; xk[7] += c.w;
    const float* q = Pv + (size_t)cs * (32 * HIDDEN);
    float4 d = *(const float4*)(q);
    float4 e = *(const float4*)(q + 4);
    xv[0] += d.x; xv[1] += d.y; xv[2] += d.z; xv[3] += d.w;
    xv[4] += e.x; xv[5] += e.y; xv[6] += e.z; xv[7] += e.w;
  }

  float ssk = 0.0f, ssv = 0.0f;
#pragma unroll
  for (int j = 0; j < 8; ++j) { ssk = fmaf(xk[j], xk[j], ssk); ssv = fmaf(xv[j], xv[j], ssv); }
#pragma unroll
  for (int off = 1; off < 16; off <<= 1) {
    ssk += __shfl_xor(ssk, off, 64);
    ssv += __shfl_xor(ssv, off, 64);
  }
  // K gets attn scale D^-0.5 folded in
  const float invk = rsqrtf(ssk * (1.0f / 128.0f) + 1e-5f) * 0.08838834764831845f;
  const float invv = rsqrtf(ssv * (1.0f / 128.0f) + 1e-5f);

  bf16x8 ko;
#pragma unroll
  for (int j = 0; j < 8; ++j) ko[j] = (bf16_t)(xk[j] * invk);
  *(bf16x8*)(K16 + (size_t)(bh * 16 + key) * DD + dpos * 8) = ko;

#pragma unroll
  for (int j = 0; j < 8; ++j) {
    int d = dpos * 8 + j;
    VT[(size_t)(bh * DD + d) * 16 + key] = (bf16_t)(xv[j] * invv);
  }
}

// ---------------------------------------------------------------------------
// Kernel B: attention. grid (18, 24, 2), block 256 (4 waves).
// Each wave processes 16 q-rows per tile, 4 tiles.
// scores^T = mfma(A=K, B=q): lane (lr,lg) holds scores[key=lg*4+e][qrow=lr]
// P repack to PV A-fragment via ds_bpermute (__shfl), no LDS, no barrier.
// PV: out = mfma(A=P, B=V^T), keys 16..31 zero-padded.
// ---------------------------------------------------------------------------
__global__ __launch_bounds__(256) void kB(const float* __restrict__ q,
                                          const bf16_t* __restrict__ K16,
                                          const bf16_t* __restrict__ VT,
                                          float* __restrict__ out) {
  const int qt = blockIdx.x, h = blockIdx.y, b = blockIdx.z;
  const int bh = b * NH + h;
  const int t = threadIdx.x;
  const int lane = t & 63, wv = t >> 6;
  const int lr = lane & 15, lg = lane >> 4;

  // K fragments (A operand of QK^T), resident for the whole block
  bf16x8 kf[4];
  const bf16_t* __restrict__ Kb = K16 + (size_t)bh * (LIP * DD);
#pragma unroll
  for (int c = 0; c < 4; ++c)
    kf[c] = *(const bf16x8*)(Kb + lr * DD + c * 32 + lg * 8);

  // V fragments (B operand of PV), resident; keys>=16 are zero padding
  bf16x8 vf[8];
  const bf16_t* __restrict__ Vb = VT + (size_t)bh * (DD * LIP);
#pragma unroll
  for (int n = 0; n < 8; ++n) {
    if (lg < 2) {
      vf[n] = *(const bf16x8*)(Vb + (size_t)(n * 16 + lr) * 16 + lg * 8);
    } else {
#pragma unroll
      for (int e = 0; e < 8; ++e) vf[n][e] = (bf16_t)0.0f;
    }
  }

  const float* __restrict__ qb = q + ((size_t)bh * LQ + qt * 256) * DD;
  float* __restrict__ ob = out + ((size_t)b * LQ + qt * 256) * HIDDEN + h * DD;

  for (int tt = wv; tt < 16; tt += 4) {
    // q fragments: B operand, B[k=c*32+lg*8+e][col=lr] = q[row0+lr][k]
    const float* qrow = qb + (size_t)(tt * 16 + lr) * DD + lg * 8;
    bf16x8 qf[4];
#pragma unroll
    for (int c = 0; c < 4; ++c) {
      float4 a = *(const float4*)(qrow + c * 32);
      float4 bq = *(const float4*)(qrow + c * 32 + 4);
      bf16x8 f;
      f[0] = (bf16_t)a.x;  f[1] = (bf16_t)a.y;
      f[2] = (bf16_t)a.z;  f[3] = (bf16_t)a.w;
      f[4] = (bf16_t)bq.x; f[5] = (bf16_t)bq.y;
      f[6] = (bf16_t)bq.z; f[7] = (bf16_t)bq.w;
      qf[c] = f;
    }

    f32x4 sc = {0.0f, 0.0f, 0.0f, 0.0f};
#pragma unroll
    for (int c = 0; c < 4; ++c)
      sc = __builtin_amdgcn_mfma_f32_16x16x32_bf16(kf[c], qf[c], sc, 0, 0, 0);

    // softmax over 16 keys for qrow lr (keys spread over lanes lr, lr+16, lr+32, lr+48)
    float m = fmaxf(fmaxf(sc[0], sc[1]), fmaxf(sc[2], sc[3]));
    m = fmaxf(m, __shfl_xor(m, 16, 64));
    m = fmaxf(m, __shfl_xor(m, 32, 64));
    float p0 = __expf(sc[0] - m), p1 = __expf(sc[1] - m);
    float p2 = __expf(sc[2] - m), p3 = __expf(sc[3] - m);
    float s = p0 + p1 + p2 + p3;
    s += __shfl_xor(s, 16, 64);
    s += __shfl_xor(s, 32, 64);
    const float inv = 1.0f / s;

    // normalized P values held by this lane: P[qrow=lr][key=lg*4+e]
    const float pn0 = p0 * inv, pn1 = p1 * inv, pn2 = p2 * inv, pn3 = p3 * inv;

    // A fragment for PV: lane (lr,lg) needs P[lr][key=(lg&1)*8+e], e=0..7.
    // Source lane for key k is  lr + (k>>2)*16, element k&3. All lanes
    // participate in every shuffle (no divergence); lg>=2 zeroed after.
    bf16x8 af;
#pragma unroll
    for (int e = 0; e < 8; ++e) {
      const int key = ((lg & 1) << 3) + e;
      const int src = lr + ((key >> 2) << 4);
      float v;
      if ((e & 3) == 0)      v = __shfl(pn0, src, 64);
      else if ((e & 3) == 1) v = __shfl(pn1, src, 64);
      else if ((e & 3) == 2) v = __shfl(pn2, src, 64);
      else                   v = __shfl(pn3, src, 64);
      af[e] = (bf16_t)v;
    }
    if (lg >= 2) {
#pragma unroll
      for (int e = 0; e < 8; ++e) af[e] = (bf16_t)0.0f;
    }

    float* orow = ob + (size_t)(tt * 16) * HIDDEN;
#pragma unroll
    for (int n = 0; n < 8; ++n) {
      f32x4 o = {0.0f, 0.0f, 0.0f, 0.0f};
      o = __builtin_amdgcn_mfma_f32_16x16x32_bf16(af, vf[n], o, 0, 0, 0);
#pragma unroll
      for (int e = 0; e < 4; ++e)
        orow[(size_t)(lg * 4 + e) * HIDDEN + n * 16 + lr] = o[e];
    }
  }
}

extern "C" void kernel_launch(void* const* d_in, const int* in_sizes, int n_in,
                              void* d_out, int out_size, void* d_ws, size_t ws_size,
                              hipStream_t stream) {
  const float* query = (const float*)d_in[0];
  const float* img   = (const float*)d_in[1];
  // d_in[2] = t (unused by the reference)
  const float* Wk    = (const float*)d_in[3];
  const float* Wv    = (const float*)d_in[4];
  // d_in[5] = num_heads (hardcoded 24)

  float*  P   = (float*)d_ws;
  bf16_t* K16 = (bf16_t*)((char*)d_ws + K16_OFF);
  bf16_t* VT  = (bf16_t*)((char*)d_ws + VT_OFF);
  float*  o   = (float*)d_out;

  hipLaunchKernelGGL(kA,  dim3(HBLKS, CS, 2), dim3(256), 0, stream, img, Wk, Wv, P);
  hipLaunchKernelGGL(kA2, dim3(NB * NH),      dim3(256), 0, stream, P, K16, VT);
  hipLaunchKernelGGL(kB,  dim3(LQ / 256, NH, NB), dim3(256), 0, stream, query, K16, VT, o);
}